// Round 13
// baseline (71.050 us; speedup 1.0000x reference)
//
#include <hip/hip_runtime.h>
#include <type_traits>

#define N_IN 2048
#define N_HID 8192
#define N_OUT 1024
#define NTOT 11264

typedef __attribute__((ext_vector_type(4))) float f32x4;
typedef __attribute__((ext_vector_type(4))) short short4v;
typedef __attribute__((ext_vector_type(8))) short short8v;
typedef __attribute__((ext_vector_type(2))) unsigned u32x2;

// f32 -> bf16 RNE (scalar, epilogue only)
__device__ inline short f2bf(float f) {
    unsigned u = __float_as_uint(f);
    return (short)((u + 0x7fffu + ((u >> 16) & 1u)) >> 16);
}

__device__ inline float bf2f(short s) {
    return __uint_as_float(((unsigned)(unsigned short)s) << 16);
}

// packed f32x2 -> bf16x2 (hardware RNE)
__device__ inline unsigned cvt_pk_bf16(float lo, float hi) {
    unsigned r;
    asm("v_cvt_pk_bf16_f32 %0, %1, %2" : "=v"(r) : "v"(lo), "v"(hi));
    return r;
}

// k-interleave within 64-wide K group: lane's 8 MFMA operand values contiguous.
__device__ inline int perm64(int c) {
    return (c & 32) + (((c >> 2) & 3) << 3) + (((c >> 4) & 1) << 2) + (c & 3);
}

__device__ inline void gload_lds16(const void* g, void* l) {
    __builtin_amdgcn_global_load_lds(
        (const __attribute__((address_space(1))) unsigned int*)g,
        (__attribute__((address_space(3))) unsigned int*)l, 16, 0, 0);
}

// ---------------------------------------------------------------------------
// x (f32) -> xb (bf16, k-interleaved), 512x2048
// ---------------------------------------------------------------------------
__global__ __launch_bounds__(256) void cvt_x(
    const float* __restrict__ x, short* __restrict__ xb)
{
    const int i = blockIdx.x * 256 + threadIdx.x;   // grid 1024
    const f32x4 v = *reinterpret_cast<const f32x4*>(x + (size_t)i * 4);
    u32x2 s;
    s[0] = cvt_pk_bf16(v[0], v[1]);
    s[1] = cvt_pk_bf16(v[2], v[3]);
    const int c0  = (i * 4) & (N_IN - 1);
    const int p   = (c0 & ~63) + perm64(c0 & 63);
    const size_t row = (size_t)(i >> 9);
    *reinterpret_cast<u32x2*>(xb + row * N_IN + p) = s;
}

// ---------------------------------------------------------------------------
// Unified GEMM (R12 core: depth-3 counted-vmcnt + XCD swizzle), plus:
//  BBF16 && FUSE : rider converts W2 (32 MiB f32) -> w2 (bf16 row-major),
//                  2 extra VMEM ops/thread in ITERs T<16 (FIFO-ledger safe).
//  BBF16 && !FUSE: B loaded from w2 as bf16 (half bytes), B_WRITE = repack
//                  (bit-identical LDS image to the f32+cvt path).
// ---------------------------------------------------------------------------
template<bool FUSE, bool BBF16>
__global__ __launch_bounds__(512, 2) void gemm_bf16(
    const short* __restrict__ A,
    const float* __restrict__ W,
    const float* __restrict__ bias,
    short* __restrict__ hOut,
    short* __restrict__ pOut,       // !FUSE: bf16 split-K partials
    short* __restrict__ w2,         // bf16 W2 [8192][1024] (rider out / B in)
    int lda, int nt, int wrow0, int wcol0)
{
    __shared__ __align__(16) short As[4][128 * 64];  // ring of 4, XOR-swizzled
    __shared__ __align__(16) short Bs[2][128][72];   // [n][perm k], stride 72

    // ---- XCD-aware decomposition of the flat 256-block grid ----
    const int bid = blockIdx.x;
    const int xcd = bid & 7;
    const int j   = bid >> 3;        // 0..31
    int bx, by, bz;
    if (FUSE) {      // logical (64 x, 4 y): 4 y-partners share B-slice
        bx = xcd * 8 + (j >> 2);
        by = j & 3;
        bz = 0;
    } else {         // logical (8 x, 4 y, 8 z): XCD owns one z split
        const int xz = xcd * 8 + (j >> 2);
        bx = xz & 7;
        bz = xz >> 3;
        by = j & 3;
    }

    const int t    = threadIdx.x;
    const int lane = t & 63;
    const int wid  = t >> 6;
    const int wr   = wid >> 2;
    const int wc   = wid & 3;
    const int brow = by * 128;
    const int bcol = bx * 128;
    const int l15  = lane & 15;
    const int lg   = lane >> 4;
    const int ks   = bz * 1024;

    const int arow = lane >> 3;
    const int asw  = ((lane & 7) * 16) ^ (arow << 4);

    const int nb   = (lane & 7) + 8 * (wid >> 1);
    const int kblk = ((lane >> 3) & 7) + 8 * (wid & 1);
    const int n0 = nb * 4, k0 = kblk * 4;
    const int p0 = perm64(k0);

    const char*  Abytes = (const char*)A;
    const size_t lda_b  = (size_t)lda * 2;

    using BT = typename std::conditional<BBF16 && !FUSE, short4v, f32x4>::type;

    f32x4 acc[4][2] = {};
    BT bv0[4], bv1[4], bv2[4], bv3[4];

    // B source: f32 W block, or bf16 w2 block (row-major [k][1024])
    const char* bSrc;
    size_t bStride;
    if (BBF16 && !FUSE) {
        bSrc = (const char*)(w2 + (size_t)(ks + k0) * 1024 + (bcol + n0));
        bStride = 1024 * 2;
    } else {
        bSrc = (const char*)&W[(size_t)(wrow0 + ks + k0) * NTOT
                               + (wcol0 + bcol + n0)];
        bStride = (size_t)NTOT * 4;
    }

#define B_LOAD(TT, BV) { \
    const char* wp = bSrc + (size_t)(TT) * 64 * bStride; \
    _Pragma("unroll") for (int jj = 0; jj < 4; ++jj) \
        BV[jj] = *reinterpret_cast<const BT*>(wp + (size_t)jj * bStride); }

#define A_LOAD(TT) { \
    char* dst = (char*)As + ((TT) & 3) * 16384; \
    _Pragma("unroll") for (int i = 0; i < 2; ++i) { \
        const int c = wid * 2 + i; \
        gload_lds16(Abytes + (size_t)(brow + c * 8 + arow) * lda_b \
                          + (size_t)(ks + (TT) * 64) * 2 + asw, \
                    dst + c * 1024); } }

#define B_WRITE(TT, BV) { \
    short* bsb = &Bs[(TT) & 1][0][0]; \
    _Pragma("unroll") for (int i = 0; i < 4; ++i) { \
        u32x2 s; \
        if constexpr (BBF16 && !FUSE) { \
            s[0] = (unsigned)(unsigned short)BV[0][i] \
                 | ((unsigned)(unsigned short)BV[1][i] << 16); \
            s[1] = (unsigned)(unsigned short)BV[2][i] \
                 | ((unsigned)(unsigned short)BV[3][i] << 16); \
        } else { \
            s[0] = cvt_pk_bf16(BV[0][i], BV[1][i]); \
            s[1] = cvt_pk_bf16(BV[2][i], BV[3][i]); \
        } \
        *reinterpret_cast<u32x2*>(bsb + (n0 + i) * 72 + p0) = s; } }

// W2->bf16 rider: 1 f32x4 read + 1 8B write per thread, ITERs T<16.
// Issued AFTER WAITV so FIFO retires them with tile T+2 (ledger-verified).
#define RIDERW(TT) { \
    if constexpr (FUSE && BBF16) { \
        if ((TT) < 16) { \
            const int f4 = (bid << 13) + (TT) * 512 + t; \
            const int rr = f4 >> 8; \
            const int cc = (f4 & 255) << 2; \
            const f32x4 wv = *reinterpret_cast<const f32x4*>( \
                &W[(size_t)(N_IN + rr) * NTOT + (N_IN + N_HID + cc)]); \
            u32x2 pk; \
            pk[0] = cvt_pk_bf16(wv[0], wv[1]); \
            pk[1] = cvt_pk_bf16(wv[2], wv[3]); \
            *reinterpret_cast<u32x2*>(w2 + ((size_t)f4 << 2)) = pk; } } }

#define COMPUTE(TT) { \
    const char*  ab = (const char*)As + ((TT) & 3) * 16384; \
    const short* bb = &Bs[(TT) & 1][0][0]; \
    short8v a[2][4], b[2][2]; \
    _Pragma("unroll") for (int g = 0; g < 2; ++g) { \
        const int koff = g * 64 + lg * 16; \
        _Pragma("unroll") for (int m = 0; m < 4; ++m) { \
            const int r = wr * 64 + m * 16 + l15; \
            a[g][m] = *reinterpret_cast<const short8v*>( \
                ab + ((r * 128 + koff) ^ ((r & 7) << 4))); } \
        _Pragma("unroll") for (int n = 0; n < 2; ++n) { \
            const int r = wc * 32 + n * 16 + l15; \
            b[g][n] = *reinterpret_cast<const short8v*>( \
                (const char*)(bb + r * 72) + koff); } } \
    __builtin_amdgcn_s_setprio(1); \
    _Pragma("unroll") for (int g = 0; g < 2; ++g) \
      _Pragma("unroll") for (int m = 0; m < 4; ++m) \
        _Pragma("unroll") for (int n = 0; n < 2; ++n) \
            acc[m][n] = __builtin_amdgcn_mfma_f32_16x16x32_bf16( \
                a[g][m], b[g][n], acc[m][n], 0, 0, 0); \
    __builtin_amdgcn_s_setprio(0); }

#define WAITV(N) { asm volatile("s_waitcnt vmcnt(" #N ")" ::: "memory"); \
                   __builtin_amdgcn_sched_barrier(0); }
#define BARRIER  { asm volatile("s_waitcnt lgkmcnt(0)" ::: "memory"); \
                   __builtin_amdgcn_sched_barrier(0); \
                   __builtin_amdgcn_s_barrier(); \
                   __builtin_amdgcn_sched_barrier(0); }

// One steady-state iteration: process T; issue T+3; retire through T+1.
#define ITER(T, BVL, BVW) { \
    B_LOAD(T + 3, BVL); A_LOAD(T + 3); \
    WAITV(12); \
    B_WRITE(T + 1, BVW); \
    RIDERW(T); \
    COMPUTE(T); \
    BARRIER; }

    // ---- prologue: tiles 0,1,2 in flight (18 loads) ----
    B_LOAD(0, bv0); A_LOAD(0);
    B_LOAD(1, bv1); A_LOAD(1);
    B_LOAD(2, bv2); A_LOAD(2);
    WAITV(12);                // tile 0 landed (1,2 still in flight)
    B_WRITE(0, bv0);
    BARRIER;

    // ---- main loop: processes 0 .. nt-5 (nt % 4 == 0) ----
    for (int tt = 0; tt + 4 < nt; tt += 4) {
        ITER(tt,     bv3, bv1);
        ITER(tt + 1, bv0, bv2);
        ITER(tt + 2, bv1, bv3);
        ITER(tt + 3, bv2, bv0);
    }
    // ---- last full iteration: processes nt-4, issues nt-1 ----
    ITER(nt - 4, bv3, bv1);

    // ---- tail: tiles nt-3, nt-2, nt-1 (all loads issued) ----
    WAITV(6);                 // tile nt-2 landed
    B_WRITE(nt - 2, bv2);
    COMPUTE(nt - 3);
    BARRIER;
    WAITV(0);                 // tile nt-1 landed
    B_WRITE(nt - 1, bv3);
    COMPUTE(nt - 2);
    BARRIER;
    COMPUTE(nt - 1);

#undef B_LOAD
#undef A_LOAD
#undef B_WRITE
#undef RIDERW
#undef COMPUTE
#undef WAITV
#undef BARRIER
#undef ITER

    if (FUSE) {
#pragma unroll
        for (int m = 0; m < 4; ++m) {
            const int row0 = brow + wr * 64 + m * 16 + lg * 4;
#pragma unroll
            for (int n = 0; n < 2; ++n) {
                const int col  = bcol + wc * 32 + n * 16 + l15;
                const int pcol = (col & ~63) + perm64(col & 63);
                const float bb = bias[N_IN + col];
#pragma unroll
                for (int q = 0; q < 4; ++q) {
                    float v = acc[m][n][q] + bb;
                    v = v > 0.f ? v : 0.f;
                    hOut[(size_t)(row0 + q) * N_HID + pcol] = f2bf(v);
                }
            }
        }
    } else {
        short* po = pOut + (size_t)bz * (512 * N_OUT);
#pragma unroll
        for (int m = 0; m < 4; ++m) {
            const int row0 = brow + wr * 64 + m * 16 + lg * 4;
#pragma unroll
            for (int n = 0; n < 2; ++n) {
                const int col = bcol + wc * 32 + n * 16 + l15;
#pragma unroll
                for (int q = 0; q < 4; ++q)
                    po[(size_t)(row0 + q) * N_OUT + col] = f2bf(acc[m][n][q]);
            }
        }
    }
}

// ---------------------------------------------------------------------------
// Reduce 8 bf16 split-K partials + output bias -> out (f32)
// ---------------------------------------------------------------------------
__global__ __launch_bounds__(256) void reduce_bias(
    const short* __restrict__ part,  // [8][512][1024] bf16
    const float* __restrict__ bias,
    float* __restrict__ out)         // [512][1024] f32
{
    const int idx = (blockIdx.x * 256 + threadIdx.x) * 4;  // grid 512
    f32x4 s = *reinterpret_cast<const f32x4*>(&bias[N_IN + N_HID + (idx & 1023)]);
#pragma unroll
    for (int sp = 0; sp < 8; ++sp) {
        const short4v p = *reinterpret_cast<const short4v*>(
            &part[(size_t)sp * 524288 + idx]);
#pragma unroll
        for (int jj = 0; jj < 4; ++jj) s[jj] += bf2f(p[jj]);
    }
    *reinterpret_cast<f32x4*>(&out[idx]) = s;
}

extern "C" void kernel_launch(void* const* d_in, const int* in_sizes, int n_in,
                              void* d_out, int out_size, void* d_ws, size_t ws_size,
                              hipStream_t stream) {
    const float* x    = (const float*)d_in[0];
    const float* W    = (const float*)d_in[1];
    const float* bias = (const float*)d_in[2];
    // d_in[3] = mask: structurally fixed 3-level DAG, never read.
    float* out = (float*)d_out;

    // ws: h @0 (8 MiB bf16), part @8MiB (8 MiB bf16, xb aliases),
    //     w2b @16MiB (16 MiB bf16 W2) -- only if ws_size >= 32 MiB.
    short* h    = (short*)d_ws;
    short* part = (short*)((char*)d_ws + (size_t)(8 << 20));
    short* xb   = (short*)((char*)d_ws + (size_t)(8 << 20));  // dead before GEMM2
    short* w2b  = (short*)((char*)d_ws + (size_t)(16 << 20));

    const bool big = ws_size >= ((size_t)32 << 20);  // fixed per-harness

    cvt_x<<<dim3(1024), dim3(256), 0, stream>>>(x, xb);

    if (big) {
        // GEMM1 + W2->bf16 rider
        gemm_bf16<true, true><<<dim3(256), dim3(512), 0, stream>>>(
            xb, W, bias, h, nullptr, w2b, N_IN, 32, 0, N_IN);
        // GEMM2 with bf16 B (half VMEM bytes)
        gemm_bf16<false, true><<<dim3(256), dim3(512), 0, stream>>>(
            h, W, nullptr, nullptr, part, w2b, N_HID, 16, N_IN, N_IN + N_HID);
    } else {
        // exact R12 fallback
        gemm_bf16<true, false><<<dim3(256), dim3(512), 0, stream>>>(
            xb, W, bias, h, nullptr, nullptr, N_IN, 32, 0, N_IN);
        gemm_bf16<false, false><<<dim3(256), dim3(512), 0, stream>>>(
            h, W, nullptr, nullptr, part, nullptr, N_HID, 16, N_IN, N_IN + N_HID);
    }

    reduce_bias<<<dim3(512), dim3(256), 0, stream>>>(part, bias, out);
}

// Round 14
// 66.737 us; speedup vs baseline: 1.0646x; 1.0646x over previous
//
#include <hip/hip_runtime.h>

#define N_IN 2048
#define N_HID 8192
#define N_OUT 1024
#define NTOT 11264

typedef __attribute__((ext_vector_type(4))) float f32x4;
typedef __attribute__((ext_vector_type(4))) short short4v;
typedef __attribute__((ext_vector_type(8))) short short8v;
typedef __attribute__((ext_vector_type(2))) unsigned u32x2;

// f32 -> bf16 RNE (scalar, epilogue only)
__device__ inline short f2bf(float f) {
    unsigned u = __float_as_uint(f);
    return (short)((u + 0x7fffu + ((u >> 16) & 1u)) >> 16);
}

__device__ inline float bf2f(short s) {
    return __uint_as_float(((unsigned)(unsigned short)s) << 16);
}

// packed f32x2 -> bf16x2 (hardware RNE)
__device__ inline unsigned cvt_pk_bf16(float lo, float hi) {
    unsigned r;
    asm("v_cvt_pk_bf16_f32 %0, %1, %2" : "=v"(r) : "v"(lo), "v"(hi));
    return r;
}

// k-interleave within 64-wide K group: lane's 8 MFMA operand values contiguous.
__device__ inline int perm64(int c) {
    return (c & 32) + (((c >> 2) & 3) << 3) + (((c >> 4) & 1) << 2) + (c & 3);
}

__device__ inline void gload_lds16(const void* g, void* l) {
    __builtin_amdgcn_global_load_lds(
        (const __attribute__((address_space(1))) unsigned int*)g,
        (__attribute__((address_space(3))) unsigned int*)l, 16, 0, 0);
}

#define WAITV(N) { asm volatile("s_waitcnt vmcnt(" #N ")" ::: "memory"); \
                   __builtin_amdgcn_sched_barrier(0); }
#define BARRIER  { asm volatile("s_waitcnt lgkmcnt(0)" ::: "memory"); \
                   __builtin_amdgcn_sched_barrier(0); \
                   __builtin_amdgcn_s_barrier(); \
                   __builtin_amdgcn_sched_barrier(0); }

// ---------------------------------------------------------------------------
// x (f32) -> xb (bf16, k-interleaved), 512x2048
// ---------------------------------------------------------------------------
__global__ __launch_bounds__(256) void cvt_x(
    const float* __restrict__ x, short* __restrict__ xb)
{
    const int i = blockIdx.x * 256 + threadIdx.x;   // grid 1024
    const f32x4 v = *reinterpret_cast<const f32x4*>(x + (size_t)i * 4);
    u32x2 s;
    s[0] = cvt_pk_bf16(v[0], v[1]);
    s[1] = cvt_pk_bf16(v[2], v[3]);
    const int c0  = (i * 4) & (N_IN - 1);
    const int p   = (c0 & ~63) + perm64(c0 & 63);
    const size_t row = (size_t)(i >> 9);
    *reinterpret_cast<u32x2*>(xb + row * N_IN + p) = s;
}

// ---------------------------------------------------------------------------
// GEMM1 (exact R12 core): H = relu(xb @ W1 + b). 128x128 tile, depth-3
// counted-vmcnt, XCD swizzle (4 y-partners per XCD share B-slice).
// ---------------------------------------------------------------------------
__global__ __launch_bounds__(512, 2) void gemm1(
    const short* __restrict__ A,
    const float* __restrict__ W,
    const float* __restrict__ bias,
    short* __restrict__ hOut)
{
    __shared__ __align__(16) short As[4][128 * 64];
    __shared__ __align__(16) short Bs[2][128][72];

    const int bid = blockIdx.x;
    const int xcd = bid & 7;
    const int j   = bid >> 3;
    const int bx  = xcd * 8 + (j >> 2);   // 0..63
    const int by  = j & 3;

    const int t    = threadIdx.x;
    const int lane = t & 63;
    const int wid  = t >> 6;
    const int wr   = wid >> 2;
    const int wc   = wid & 3;
    const int brow = by * 128;
    const int bcol = bx * 128;
    const int l15  = lane & 15;
    const int lg   = lane >> 4;

    const int arow = lane >> 3;
    const int asw  = ((lane & 7) * 16) ^ (arow << 4);

    const int nb   = (lane & 7) + 8 * (wid >> 1);
    const int kblk = ((lane >> 3) & 7) + 8 * (wid & 1);
    const int n0 = nb * 4, k0 = kblk * 4;
    const int p0 = perm64(k0);

    const char*  Abytes = (const char*)A;
    const size_t lda_b  = (size_t)N_IN * 2;

    f32x4 acc[4][2] = {};
    f32x4 bv0[4], bv1[4], bv2[4], bv3[4];

    const float* wp0 = &W[(size_t)k0 * NTOT + (N_IN + bcol + n0)];

#define B_LOAD(TT, BV) { \
    const float* wp = wp0 + (size_t)(TT) * 64 * NTOT; \
    _Pragma("unroll") for (int jj = 0; jj < 4; ++jj) \
        BV[jj] = *reinterpret_cast<const f32x4*>(wp + (size_t)jj * NTOT); }

#define A_LOAD(TT) { \
    char* dst = (char*)As + ((TT) & 3) * 16384; \
    _Pragma("unroll") for (int i = 0; i < 2; ++i) { \
        const int c = wid * 2 + i; \
        gload_lds16(Abytes + (size_t)(brow + c * 8 + arow) * lda_b \
                          + (size_t)((TT) * 64) * 2 + asw, \
                    dst + c * 1024); } }

#define B_WRITE(TT, BV) { \
    short* bsb = &Bs[(TT) & 1][0][0]; \
    _Pragma("unroll") for (int i = 0; i < 4; ++i) { \
        u32x2 s; \
        s[0] = cvt_pk_bf16(BV[0][i], BV[1][i]); \
        s[1] = cvt_pk_bf16(BV[2][i], BV[3][i]); \
        *reinterpret_cast<u32x2*>(bsb + (n0 + i) * 72 + p0) = s; } }

#define COMPUTE(TT) { \
    const char*  ab = (const char*)As + ((TT) & 3) * 16384; \
    const short* bb = &Bs[(TT) & 1][0][0]; \
    short8v a[2][4], b[2][2]; \
    _Pragma("unroll") for (int g = 0; g < 2; ++g) { \
        const int koff = g * 64 + lg * 16; \
        _Pragma("unroll") for (int m = 0; m < 4; ++m) { \
            const int r = wr * 64 + m * 16 + l15; \
            a[g][m] = *reinterpret_cast<const short8v*>( \
                ab + ((r * 128 + koff) ^ ((r & 7) << 4))); } \
        _Pragma("unroll") for (int n = 0; n < 2; ++n) { \
            const int r = wc * 32 + n * 16 + l15; \
            b[g][n] = *reinterpret_cast<const short8v*>( \
                (const char*)(bb + r * 72) + koff); } } \
    __builtin_amdgcn_s_setprio(1); \
    _Pragma("unroll") for (int g = 0; g < 2; ++g) \
      _Pragma("unroll") for (int m = 0; m < 4; ++m) \
        _Pragma("unroll") for (int n = 0; n < 2; ++n) \
            acc[m][n] = __builtin_amdgcn_mfma_f32_16x16x32_bf16( \
                a[g][m], b[g][n], acc[m][n], 0, 0, 0); \
    __builtin_amdgcn_s_setprio(0); }

#define ITER(T, BVL, BVW) { \
    B_LOAD(T + 3, BVL); A_LOAD(T + 3); \
    WAITV(12); \
    B_WRITE(T + 1, BVW); \
    COMPUTE(T); \
    BARRIER; }

    B_LOAD(0, bv0); A_LOAD(0);
    B_LOAD(1, bv1); A_LOAD(1);
    B_LOAD(2, bv2); A_LOAD(2);
    WAITV(12);
    B_WRITE(0, bv0);
    BARRIER;

    const int nt = 32;
    for (int tt = 0; tt + 4 < nt; tt += 4) {
        ITER(tt,     bv3, bv1);
        ITER(tt + 1, bv0, bv2);
        ITER(tt + 2, bv1, bv3);
        ITER(tt + 3, bv2, bv0);
    }
    ITER(nt - 4, bv3, bv1);

    WAITV(6);
    B_WRITE(nt - 2, bv2);
    COMPUTE(nt - 3);
    BARRIER;
    WAITV(0);
    B_WRITE(nt - 1, bv3);
    COMPUTE(nt - 2);
    BARRIER;
    COMPUTE(nt - 1);

#undef B_LOAD
#undef A_LOAD
#undef B_WRITE
#undef COMPUTE
#undef ITER

#pragma unroll
    for (int m = 0; m < 4; ++m) {
        const int row0 = brow + wr * 64 + m * 16 + lg * 4;
#pragma unroll
        for (int n = 0; n < 2; ++n) {
            const int col  = bcol + wc * 32 + n * 16 + l15;
            const int pcol = (col & ~63) + perm64(col & 63);
            const float bb = bias[N_IN + col];
#pragma unroll
            for (int q = 0; q < 4; ++q) {
                float v = acc[m][n][q] + bb;
                v = v > 0.f ? v : 0.f;
                hOut[(size_t)(row0 + q) * N_HID + pcol] = f2bf(v);
            }
        }
    }
}

// ---------------------------------------------------------------------------
// GEMM2: 256x64 tile, grid 16x * 2y * 8z (z == XCD: W2 z-slice 4MiB + h
// z-slice 1MiB stay L2-local; B duplication halved). Same depth-3 FIFO:
// 6 VMEM/tile (4 A-DMA + 2 B), WAITV(12)/(6)/(0). acc 4x2, 8 waves 4wr x 2wc.
// ---------------------------------------------------------------------------
__global__ __launch_bounds__(512, 2) void gemm2(
    const short* __restrict__ A,    // h, bf16 [512][8192] (perm'd cols)
    const float* __restrict__ W,
    short* __restrict__ pOut)       // bf16 partials [8][512][1024]
{
    __shared__ __align__(16) short As[4][256 * 64];  // 128 KB ring
    __shared__ __align__(16) short Bs[2][64][72];    // 18 KB

    const int bid = blockIdx.x;
    const int bz  = bid & 7;         // z-split == XCD
    const int j   = bid >> 3;
    const int bx  = j >> 1;          // 0..15
    const int by  = j & 1;           // 0..1

    const int t    = threadIdx.x;
    const int lane = t & 63;
    const int wid  = t >> 6;
    const int wr   = wid >> 1;       // 0..3
    const int wc   = wid & 1;        // 0..1
    const int brow = by * 256;
    const int bcol = bx * 64;
    const int l15  = lane & 15;
    const int lg   = lane >> 4;
    const int ks   = bz * 1024;

    const int arow = lane >> 3;
    const int asw  = ((lane & 7) * 16) ^ (arow << 4);

    // B staging: thread owns 2 k-rows x 4 n-cols
    const int k2 = (t >> 4) * 2;     // 0..62 (even)
    const int n0 = (t & 15) * 4;     // 0..60
    const int p2 = perm64(k2);       // k2,k2+1 -> p2,p2+1 (even)

    const char*  Abytes = (const char*)A;
    const size_t lda_b  = (size_t)N_HID * 2;

    f32x4 acc[4][2] = {};
    f32x4 bv0[2], bv1[2], bv2[2], bv3[2];

    const float* wp0 = &W[(size_t)(N_IN + ks + k2) * NTOT
                          + (N_IN + N_HID + bcol + n0)];

#define B_LOAD(TT, BV) { \
    const float* wp = wp0 + (size_t)(TT) * 64 * NTOT; \
    BV[0] = *reinterpret_cast<const f32x4*>(wp); \
    BV[1] = *reinterpret_cast<const f32x4*>(wp + NTOT); }

#define A_LOAD(TT) { \
    char* dst = (char*)As + ((TT) & 3) * 32768; \
    _Pragma("unroll") for (int i = 0; i < 4; ++i) { \
        const int c = wid * 4 + i; \
        gload_lds16(Abytes + (size_t)(brow + c * 8 + arow) * lda_b \
                          + (size_t)(ks + (TT) * 64) * 2 + asw, \
                    dst + c * 1024); } }

#define B_WRITE(TT, BV) { \
    short* bsb = &Bs[(TT) & 1][0][0]; \
    _Pragma("unroll") for (int i = 0; i < 4; ++i) { \
        unsigned s = cvt_pk_bf16(BV[0][i], BV[1][i]); \
        *reinterpret_cast<unsigned*>(bsb + (n0 + i) * 72 + p2) = s; } }

#define COMPUTE(TT) { \
    const char*  ab = (const char*)As + ((TT) & 3) * 32768; \
    const short* bb = &Bs[(TT) & 1][0][0]; \
    short8v a[2][4], b[2][2]; \
    _Pragma("unroll") for (int g = 0; g < 2; ++g) { \
        const int koff = g * 64 + lg * 16; \
        _Pragma("unroll") for (int m = 0; m < 4; ++m) { \
            const int r = wr * 64 + m * 16 + l15; \
            a[g][m] = *reinterpret_cast<const short8v*>( \
                ab + ((r * 128 + koff) ^ ((r & 7) << 4))); } \
        _Pragma("unroll") for (int n = 0; n < 2; ++n) { \
            const int r = wc * 32 + n * 16 + l15; \
            b[g][n] = *reinterpret_cast<const short8v*>( \
                (const char*)(bb + r * 72) + koff); } } \
    __builtin_amdgcn_s_setprio(1); \
    _Pragma("unroll") for (int g = 0; g < 2; ++g) \
      _Pragma("unroll") for (int m = 0; m < 4; ++m) \
        _Pragma("unroll") for (int n = 0; n < 2; ++n) \
            acc[m][n] = __builtin_amdgcn_mfma_f32_16x16x32_bf16( \
                a[g][m], b[g][n], acc[m][n], 0, 0, 0); \
    __builtin_amdgcn_s_setprio(0); }

#define ITER(T, BVL, BVW) { \
    B_LOAD(T + 3, BVL); A_LOAD(T + 3); \
    WAITV(12); \
    B_WRITE(T + 1, BVW); \
    COMPUTE(T); \
    BARRIER; }

    B_LOAD(0, bv0); A_LOAD(0);
    B_LOAD(1, bv1); A_LOAD(1);
    B_LOAD(2, bv2); A_LOAD(2);
    WAITV(12);
    B_WRITE(0, bv0);
    BARRIER;

    const int nt = 16;
    for (int tt = 0; tt + 4 < nt; tt += 4) {
        ITER(tt,     bv3, bv1);
        ITER(tt + 1, bv0, bv2);
        ITER(tt + 2, bv1, bv3);
        ITER(tt + 3, bv2, bv0);
    }
    ITER(nt - 4, bv3, bv1);

    WAITV(6);
    B_WRITE(nt - 2, bv2);
    COMPUTE(nt - 3);
    BARRIER;
    WAITV(0);
    B_WRITE(nt - 1, bv3);
    COMPUTE(nt - 2);
    BARRIER;
    COMPUTE(nt - 1);

#undef B_LOAD
#undef A_LOAD
#undef B_WRITE
#undef COMPUTE
#undef ITER

    short* po = pOut + (size_t)bz * (512 * N_OUT);
#pragma unroll
    for (int m = 0; m < 4; ++m) {
        const int row0 = brow + wr * 64 + m * 16 + lg * 4;
#pragma unroll
        for (int n = 0; n < 2; ++n) {
            const int col = bcol + wc * 32 + n * 16 + l15;
#pragma unroll
            for (int q = 0; q < 4; ++q)
                po[(size_t)(row0 + q) * N_OUT + col] = f2bf(acc[m][n][q]);
        }
    }
}

// ---------------------------------------------------------------------------
// Reduce 8 bf16 split-K partials + output bias -> out (f32)
// ---------------------------------------------------------------------------
__global__ __launch_bounds__(256) void reduce_bias(
    const short* __restrict__ part,  // [8][512][1024] bf16
    const float* __restrict__ bias,
    float* __restrict__ out)         // [512][1024] f32
{
    const int idx = (blockIdx.x * 256 + threadIdx.x) * 4;  // grid 512
    f32x4 s = *reinterpret_cast<const f32x4*>(&bias[N_IN + N_HID + (idx & 1023)]);
#pragma unroll
    for (int sp = 0; sp < 8; ++sp) {
        const short4v p = *reinterpret_cast<const short4v*>(
            &part[(size_t)sp * 524288 + idx]);
#pragma unroll
        for (int jj = 0; jj < 4; ++jj) s[jj] += bf2f(p[jj]);
    }
    *reinterpret_cast<f32x4*>(&out[idx]) = s;
}

extern "C" void kernel_launch(void* const* d_in, const int* in_sizes, int n_in,
                              void* d_out, int out_size, void* d_ws, size_t ws_size,
                              hipStream_t stream) {
    const float* x    = (const float*)d_in[0];
    const float* W    = (const float*)d_in[1];
    const float* bias = (const float*)d_in[2];
    // d_in[3] = mask: structurally fixed 3-level DAG, never read.
    float* out = (float*)d_out;

    // ws: h @0 (8 MiB bf16), part @8MiB (8 MiB bf16), xb aliases part
    short* h    = (short*)d_ws;
    short* part = (short*)((char*)d_ws + (size_t)(8 << 20));
    short* xb   = (short*)((char*)d_ws + (size_t)(8 << 20));  // dead before GEMM2

    cvt_x<<<dim3(1024), dim3(256), 0, stream>>>(x, xb);

    // GEMM1: H = relu(xb @ W[0:2048, 2048:10240] + b), M=512 N=8192 K=2048
    gemm1<<<dim3(256), dim3(512), 0, stream>>>(xb, W, bias, h);

    // GEMM2: part[z] = H[:, z*1024:+1024] @ W[2048+z*1024:+1024, 10240:11264]
    gemm2<<<dim3(256), dim3(512), 0, stream>>>(h, W, part);

    reduce_bias<<<dim3(512), dim3(256), 0, stream>>>(part, bias, out);
}

// Round 15
// 59.359 us; speedup vs baseline: 1.1970x; 1.1243x over previous
//
#include <hip/hip_runtime.h>

#define N_IN 2048
#define N_HID 8192
#define N_OUT 1024
#define NTOT 11264

typedef __attribute__((ext_vector_type(4))) float f32x4;
typedef __attribute__((ext_vector_type(4))) short short4v;
typedef __attribute__((ext_vector_type(8))) short short8v;
typedef __attribute__((ext_vector_type(2))) unsigned u32x2;

// f32 -> bf16 RNE (scalar, epilogue only)
__device__ inline short f2bf(float f) {
    unsigned u = __float_as_uint(f);
    return (short)((u + 0x7fffu + ((u >> 16) & 1u)) >> 16);
}

__device__ inline float bf2f(short s) {
    return __uint_as_float(((unsigned)(unsigned short)s) << 16);
}

// packed f32x2 -> bf16x2 (hardware RNE)
__device__ inline unsigned cvt_pk_bf16(float lo, float hi) {
    unsigned r;
    asm("v_cvt_pk_bf16_f32 %0, %1, %2" : "=v"(r) : "v"(lo), "v"(hi));
    return r;
}

// k-interleave within 64-wide K group: lane's 8 MFMA operand values contiguous.
__device__ inline int perm64(int c) {
    return (c & 32) + (((c >> 2) & 3) << 3) + (((c >> 4) & 1) << 2) + (c & 3);
}

__device__ inline void gload_lds16(const void* g, void* l) {
    __builtin_amdgcn_global_load_lds(
        (const __attribute__((address_space(1))) unsigned int*)g,
        (__attribute__((address_space(3))) unsigned int*)l, 16, 0, 0);
}

#define WAITV(N) { asm volatile("s_waitcnt vmcnt(" #N ")" ::: "memory"); \
                   __builtin_amdgcn_sched_barrier(0); }
#define BARRIER  { asm volatile("s_waitcnt lgkmcnt(0)" ::: "memory"); \
                   __builtin_amdgcn_sched_barrier(0); \
                   __builtin_amdgcn_s_barrier(); \
                   __builtin_amdgcn_sched_barrier(0); }

// ---------------------------------------------------------------------------
// GEMM1 (fused x->bf16): H = relu(x @ W1 + b). 128x128 tile, depth-3-issue
// counted-vmcnt FIFO, XCD swizzle. A reg-staged from x (f32) with cvt_pk and
// swizzled ds_write (LDS image bit-identical to the R12 xb path).
// Regs: B period-3 (bv0..2), A period-2 (av0..1); As LDS ring-2.
// ---------------------------------------------------------------------------
__global__ __launch_bounds__(512, 2) void gemm1(
    const float* __restrict__ x,     // [512][2048] f32
    const float* __restrict__ W,
    const float* __restrict__ bias,
    short* __restrict__ hOut)
{
    __shared__ __align__(16) short As[2][128 * 64];  // 32 KB ring-2, swizzled
    __shared__ __align__(16) short Bs[2][128][72];   // 36 KB, [n][perm k]

    const int bid = blockIdx.x;
    const int xcd = bid & 7;
    const int j   = bid >> 3;
    const int bx  = xcd * 8 + (j >> 2);   // 0..63
    const int by  = j & 3;

    const int t    = threadIdx.x;
    const int lane = t & 63;
    const int wid  = t >> 6;
    const int wr   = wid >> 2;
    const int wc   = wid & 3;
    const int brow = by * 128;
    const int bcol = bx * 128;
    const int l15  = lane & 15;
    const int lg   = lane >> 4;

    // A staging (reg): thread owns row r = t>>2, cols kq..kq+15 of each tile
    const int ar = t >> 2;           // 0..127
    const int kq = (t & 3) * 16;     // 0,16,32,48
    const int pbase = ((kq & 32) + ((kq >> 4) & 1) * 4) * 2;  // byte offset
    const int arx = (ar & 7) << 4;   // row XOR
    const float* xrow = x + (size_t)(brow + ar) * N_IN + kq;

    // B staging: thread owns 4k x 4n block
    const int nb   = (lane & 7) + 8 * (wid >> 1);
    const int kblk = ((lane >> 3) & 7) + 8 * (wid & 1);
    const int n0 = nb * 4, k0 = kblk * 4;
    const int p0 = perm64(k0);

    f32x4 acc[4][2] = {};
    f32x4 bv0[4], bv1[4], bv2[4];
    f32x4 av0[4], av1[4];

    const float* wp0 = &W[(size_t)k0 * NTOT + (N_IN + bcol + n0)];

#define B_LOAD(TT, BV) { \
    const float* wp = wp0 + (size_t)(TT) * 64 * NTOT; \
    _Pragma("unroll") for (int jj = 0; jj < 4; ++jj) \
        BV[jj] = *reinterpret_cast<const f32x4*>(wp + (size_t)jj * NTOT); }

#define A_LOADR(TT, AV) { \
    const float* xp = xrow + (TT) * 64; \
    _Pragma("unroll") for (int jj = 0; jj < 4; ++jj) \
        AV[jj] = *reinterpret_cast<const f32x4*>(xp + jj * 4); }

#define A_WRITE(TT, AV) { \
    char* dst = (char*)As + ((TT) & 1) * 16384; \
    _Pragma("unroll") for (int jj = 0; jj < 4; ++jj) { \
        u32x2 s; \
        s[0] = cvt_pk_bf16(AV[jj][0], AV[jj][1]); \
        s[1] = cvt_pk_bf16(AV[jj][2], AV[jj][3]); \
        *reinterpret_cast<u32x2*>( \
            dst + ((ar * 128 + pbase + jj * 16) ^ arx)) = s; } }

#define B_WRITE(TT, BV) { \
    short* bsb = &Bs[(TT) & 1][0][0]; \
    _Pragma("unroll") for (int i = 0; i < 4; ++i) { \
        u32x2 s; \
        s[0] = cvt_pk_bf16(BV[0][i], BV[1][i]); \
        s[1] = cvt_pk_bf16(BV[2][i], BV[3][i]); \
        *reinterpret_cast<u32x2*>(bsb + (n0 + i) * 72 + p0) = s; } }

#define COMPUTE(TT) { \
    const char*  ab = (const char*)As + ((TT) & 1) * 16384; \
    const short* bb = &Bs[(TT) & 1][0][0]; \
    short8v a[2][4], b[2][2]; \
    _Pragma("unroll") for (int g = 0; g < 2; ++g) { \
        const int koff = g * 64 + lg * 16; \
        _Pragma("unroll") for (int m = 0; m < 4; ++m) { \
            const int r = wr * 64 + m * 16 + l15; \
            a[g][m] = *reinterpret_cast<const short8v*>( \
                ab + ((r * 128 + koff) ^ ((r & 7) << 4))); } \
        _Pragma("unroll") for (int n = 0; n < 2; ++n) { \
            const int r = wc * 32 + n * 16 + l15; \
            b[g][n] = *reinterpret_cast<const short8v*>( \
                (const char*)(bb + r * 72) + koff); } } \
    __builtin_amdgcn_s_setprio(1); \
    _Pragma("unroll") for (int g = 0; g < 2; ++g) \
      _Pragma("unroll") for (int m = 0; m < 4; ++m) \
        _Pragma("unroll") for (int n = 0; n < 2; ++n) \
            acc[m][n] = __builtin_amdgcn_mfma_f32_16x16x32_bf16( \
                a[g][m], b[g][n], acc[m][n], 0, 0, 0); \
    __builtin_amdgcn_s_setprio(0); }

// ITER(T): queue [B(T+2),A(T+1)] -> issue B(T+3),A(T+2) -> WAITV(8) retires
// B(T+2),A(T+1) -> write tile T+1 -> compute T -> barrier.
#define ITER(T, BVL, AVL, AVW, BVW) { \
    B_LOAD(T + 3, BVL); \
    A_LOADR(T + 2, AVL); \
    WAITV(8); \
    A_WRITE(T + 1, AVW); \
    B_WRITE(T + 1, BVW); \
    COMPUTE(T); \
    BARRIER; }

    // ---- prologue: B0,A0,B1,A1,B2 issued (20 ops); retire B0,A0 ----
    B_LOAD(0, bv0);
    A_LOADR(0, av0);
    B_LOAD(1, bv1);
    A_LOADR(1, av1);
    B_LOAD(2, bv2);
    WAITV(12);
    A_WRITE(0, av0);
    B_WRITE(0, bv0);
    BARRIER;

    // ---- main: ITERs T=0..23 (unroll 6: A period 2, B period 3) ----
    for (int tt = 0; tt < 24; tt += 6) {
        ITER(tt,     bv0, av0, av1, bv1);
        ITER(tt + 1, bv1, av1, av0, bv2);
        ITER(tt + 2, bv2, av0, av1, bv0);
        ITER(tt + 3, bv0, av1, av0, bv1);
        ITER(tt + 4, bv1, av0, av1, bv2);
        ITER(tt + 5, bv2, av1, av0, bv0);
    }
    // ---- peel T=24..28 (same 24%6==0 pattern; last load is B(31)/A(30)) ----
    ITER(24, bv0, av0, av1, bv1);
    ITER(25, bv1, av1, av0, bv2);
    ITER(26, bv2, av0, av1, bv0);
    ITER(27, bv0, av1, av0, bv1);
    ITER(28, bv1, av0, av1, bv2);

    // ---- tail T=29,30,31: entry queue [B31(bv1-loaded? no: in flight),A30] --
    // outstanding here: [B(31) in bv1? B(31) loaded at ITER(28) into bv1]
    A_LOADR(31, av1);        // av1 free (A29 written at ITER(28))
    WAITV(4);                // retires B(31), A(30); leaves A(31)
    A_WRITE(30, av0);
    B_WRITE(30, bv0);        // B(30)->bv[30%3]=bv0, retired at ITER(28)
    COMPUTE(29);
    BARRIER;
    WAITV(0);                // retire A(31)
    A_WRITE(31, av1);
    B_WRITE(31, bv1);        // B(31)->bv[31%3]=bv1
    COMPUTE(30);
    BARRIER;
    COMPUTE(31);

#undef B_LOAD
#undef A_LOADR
#undef A_WRITE
#undef B_WRITE
#undef COMPUTE
#undef ITER

    // ---- epilogue: relu(acc+bias) -> h bf16, perm'd cols ----
#pragma unroll
    for (int m = 0; m < 4; ++m) {
        const int row0 = brow + wr * 64 + m * 16 + lg * 4;
#pragma unroll
        for (int n = 0; n < 2; ++n) {
            const int col  = bcol + wc * 32 + n * 16 + l15;
            const int pcol = (col & ~63) + perm64(col & 63);
            const float bb = bias[N_IN + col];
#pragma unroll
            for (int q = 0; q < 4; ++q) {
                float v = acc[m][n][q] + bb;
                v = v > 0.f ? v : 0.f;
                hOut[(size_t)(row0 + q) * N_HID + pcol] = f2bf(v);
            }
        }
    }
}

// ---------------------------------------------------------------------------
// GEMM2 (exact R12 champion form): part[z] = H[:,z*1024:+1024] @ W2-slice.
// 128x128 tile, depth-3 counted-vmcnt, XCD swizzle (XCD owns one z-split).
// ---------------------------------------------------------------------------
__global__ __launch_bounds__(512, 2) void gemm2(
    const short* __restrict__ A,    // h, bf16 [512][8192] perm'd cols
    const float* __restrict__ W,
    short* __restrict__ pOut)       // bf16 partials [8][512][1024]
{
    __shared__ __align__(16) short As[4][128 * 64];
    __shared__ __align__(16) short Bs[2][128][72];

    const int bid = blockIdx.x;
    const int xcd = bid & 7;
    const int j   = bid >> 3;
    const int xz  = xcd * 8 + (j >> 2);
    const int bx  = xz & 7;
    const int bz  = xz >> 3;         // == xcd
    const int by  = j & 3;

    const int t    = threadIdx.x;
    const int lane = t & 63;
    const int wid  = t >> 6;
    const int wr   = wid >> 2;
    const int wc   = wid & 3;
    const int brow = by * 128;
    const int bcol = bx * 128;
    const int l15  = lane & 15;
    const int lg   = lane >> 4;
    const int ks   = bz * 1024;

    const int arow = lane >> 3;
    const int asw  = ((lane & 7) * 16) ^ (arow << 4);

    const int nb   = (lane & 7) + 8 * (wid >> 1);
    const int kblk = ((lane >> 3) & 7) + 8 * (wid & 1);
    const int n0 = nb * 4, k0 = kblk * 4;
    const int p0 = perm64(k0);

    const char*  Abytes = (const char*)A;
    const size_t lda_b  = (size_t)N_HID * 2;

    f32x4 acc[4][2] = {};
    f32x4 bv0[4], bv1[4], bv2[4], bv3[4];

    const float* wp0 = &W[(size_t)(N_IN + ks + k0) * NTOT
                          + (N_IN + N_HID + bcol + n0)];

#define B_LOAD(TT, BV) { \
    const float* wp = wp0 + (size_t)(TT) * 64 * NTOT; \
    _Pragma("unroll") for (int jj = 0; jj < 4; ++jj) \
        BV[jj] = *reinterpret_cast<const f32x4*>(wp + (size_t)jj * NTOT); }

#define A_LOAD(TT) { \
    char* dst = (char*)As + ((TT) & 3) * 16384; \
    _Pragma("unroll") for (int i = 0; i < 2; ++i) { \
        const int c = wid * 2 + i; \
        gload_lds16(Abytes + (size_t)(brow + c * 8 + arow) * lda_b \
                          + (size_t)(ks + (TT) * 64) * 2 + asw, \
                    dst + c * 1024); } }

#define B_WRITE(TT, BV) { \
    short* bsb = &Bs[(TT) & 1][0][0]; \
    _Pragma("unroll") for (int i = 0; i < 4; ++i) { \
        u32x2 s; \
        s[0] = cvt_pk_bf16(BV[0][i], BV[1][i]); \
        s[1] = cvt_pk_bf16(BV[2][i], BV[3][i]); \
        *reinterpret_cast<u32x2*>(bsb + (n0 + i) * 72 + p0) = s; } }

#define COMPUTE(TT) { \
    const char*  ab = (const char*)As + ((TT) & 3) * 16384; \
    const short* bb = &Bs[(TT) & 1][0][0]; \
    short8v a[2][4], b[2][2]; \
    _Pragma("unroll") for (int g = 0; g < 2; ++g) { \
        const int koff = g * 64 + lg * 16; \
        _Pragma("unroll") for (int m = 0; m < 4; ++m) { \
            const int r = wr * 64 + m * 16 + l15; \
            a[g][m] = *reinterpret_cast<const short8v*>( \
                ab + ((r * 128 + koff) ^ ((r & 7) << 4))); } \
        _Pragma("unroll") for (int n = 0; n < 2; ++n) { \
            const int r = wc * 32 + n * 16 + l15; \
            b[g][n] = *reinterpret_cast<const short8v*>( \
                (const char*)(bb + r * 72) + koff); } } \
    __builtin_amdgcn_s_setprio(1); \
    _Pragma("unroll") for (int g = 0; g < 2; ++g) \
      _Pragma("unroll") for (int m = 0; m < 4; ++m) \
        _Pragma("unroll") for (int n = 0; n < 2; ++n) \
            acc[m][n] = __builtin_amdgcn_mfma_f32_16x16x32_bf16( \
                a[g][m], b[g][n], acc[m][n], 0, 0, 0); \
    __builtin_amdgcn_s_setprio(0); }

#define ITER(T, BVL, BVW) { \
    B_LOAD(T + 3, BVL); A_LOAD(T + 3); \
    WAITV(12); \
    B_WRITE(T + 1, BVW); \
    COMPUTE(T); \
    BARRIER; }

    B_LOAD(0, bv0); A_LOAD(0);
    B_LOAD(1, bv1); A_LOAD(1);
    B_LOAD(2, bv2); A_LOAD(2);
    WAITV(12);
    B_WRITE(0, bv0);
    BARRIER;

    const int nt = 16;
    for (int tt = 0; tt + 4 < nt; tt += 4) {
        ITER(tt,     bv3, bv1);
        ITER(tt + 1, bv0, bv2);
        ITER(tt + 2, bv1, bv3);
        ITER(tt + 3, bv2, bv0);
    }
    ITER(nt - 4, bv3, bv1);

    WAITV(6);
    B_WRITE(nt - 2, bv2);
    COMPUTE(nt - 3);
    BARRIER;
    WAITV(0);
    B_WRITE(nt - 1, bv3);
    COMPUTE(nt - 2);
    BARRIER;
    COMPUTE(nt - 1);

#undef B_LOAD
#undef A_LOAD
#undef B_WRITE
#undef COMPUTE
#undef ITER

    short* po = pOut + (size_t)bz * (512 * N_OUT);
#pragma unroll
    for (int m = 0; m < 4; ++m) {
        const int row0 = brow + wr * 64 + m * 16 + lg * 4;
#pragma unroll
        for (int n = 0; n < 2; ++n) {
            const int col = bcol + wc * 32 + n * 16 + l15;
#pragma unroll
            for (int q = 0; q < 4; ++q)
                po[(size_t)(row0 + q) * N_OUT + col] = f2bf(acc[m][n][q]);
        }
    }
}

// ---------------------------------------------------------------------------
// Reduce 8 bf16 split-K partials + output bias -> out (f32)
// ---------------------------------------------------------------------------
__global__ __launch_bounds__(256) void reduce_bias(
    const short* __restrict__ part,  // [8][512][1024] bf16
    const float* __restrict__ bias,
    float* __restrict__ out)         // [512][1024] f32
{
    const int idx = (blockIdx.x * 256 + threadIdx.x) * 4;  // grid 512
    f32x4 s = *reinterpret_cast<const f32x4*>(&bias[N_IN + N_HID + (idx & 1023)]);
#pragma unroll
    for (int sp = 0; sp < 8; ++sp) {
        const short4v p = *reinterpret_cast<const short4v*>(
            &part[(size_t)sp * 524288 + idx]);
#pragma unroll
        for (int jj = 0; jj < 4; ++jj) s[jj] += bf2f(p[jj]);
    }
    *reinterpret_cast<f32x4*>(&out[idx]) = s;
}

extern "C" void kernel_launch(void* const* d_in, const int* in_sizes, int n_in,
                              void* d_out, int out_size, void* d_ws, size_t ws_size,
                              hipStream_t stream) {
    const float* x    = (const float*)d_in[0];
    const float* W    = (const float*)d_in[1];
    const float* bias = (const float*)d_in[2];
    // d_in[3] = mask: structurally fixed 3-level DAG, never read.
    float* out = (float*)d_out;

    // ws: h @0 (8 MiB bf16), part @8MiB (8 MiB bf16). (xb eliminated.)
    short* h    = (short*)d_ws;
    short* part = (short*)((char*)d_ws + (size_t)(8 << 20));

    // GEMM1 (x->bf16 fused): H = relu(x @ W[0:2048, 2048:10240] + b)
    gemm1<<<dim3(256), dim3(512), 0, stream>>>(x, W, bias, h);

    // GEMM2: part[z] = H[:, z*1024:+1024] @ W[2048+z*1024:+1024, 10240:11264]
    gemm2<<<dim3(256), dim3(512), 0, stream>>>(h, W, part);

    reduce_bias<<<dim3(512), dim3(256), 0, stream>>>(part, bias, out);
}